// Round 1
// baseline (15.354 us; speedup 1.0000x reference)
//
#include <hip/hip_runtime.h>

namespace {

constexpr int MAXL = 3;
constexpr int NL   = 20;   // len(L_LIST)
constexpr int NC   = 16;   // channels
constexpr int K2   = 3;
constexpr int K3   = 4;
constexpr int NKOUT = 1 + K2 + K3;  // 8 output "l" slots
constexpr int NT2  = 19;
constexpr int NT3  = 189;

constexpr int fact(int k) { return k <= 1 ? 1 : k * fact(k - 1); }

// Mirrors Python _l_list ordering: l ascending, lx descending, ly descending.
constexpr int lindex(int lx, int ly, int lz) {
  int idx = 0;
  for (int l = 0; l <= MAXL; ++l)
    for (int ax = l; ax >= 0; --ax)
      for (int ay = l - ax; ay >= 0; --ay) {
        int az = l - ax - ay;
        if (ax == lx && ay == ly && az == lz) return idx;
        ++idx;
      }
  return -1;
}

struct T2 { int i; int key; float p; };
struct Tab2 { T2 t[NT2]; };
constexpr Tab2 build2() {
  Tab2 o{}; int n = 0; int key = 0;
  for (int l = 1; l <= MAXL; ++l) {
    for (int ax = 0; ax <= l; ++ax)
      for (int ay = 0; ay <= l - ax; ++ay) {
        int az = l - ax - ay;
        int p = fact(l) / (fact(ax) * fact(ay) * fact(az));
        o.t[n].i = lindex(ax, ay, az);
        o.t[n].key = key;
        o.t[n].p = (float)p;
        ++n;
      }
    ++key;
  }
  return o;
}
constexpr Tab2 TAB2 = build2();

struct T3 { int i0, i1, i2, key; float p; };
struct Tab3 { T3 t[NT3]; };
constexpr Tab3 build3() {
  Tab3 o{}; int n = 0; int key = 0;
  for (int k12 = 1; k12 <= MAXL; ++k12)
  for (int k23 = 1; k23 <= MAXL; ++k23)
  for (int k13 = 1; k13 <= MAXL; ++k13) {
    if (k12 + k13 > MAXL || k12 + k23 > MAXL || k23 + k13 > MAXL) continue;
    for (int ax = 0; ax <= k12; ++ax)
    for (int ay = 0; ay <= k12 - ax; ++ay) {
      int az = k12 - ax - ay;
      int pa = fact(k12) / (fact(ax) * fact(ay) * fact(az));
      for (int bx = 0; bx <= k23; ++bx)
      for (int by = 0; by <= k23 - bx; ++by) {
        int bz = k23 - bx - by;
        int pb = fact(k23) / (fact(bx) * fact(by) * fact(bz));
        for (int cx = 0; cx <= k13; ++cx)
        for (int cy = 0; cy <= k13 - cx; ++cy) {
          int cz = k13 - cx - cy;
          int pc = fact(k13) / (fact(cx) * fact(cy) * fact(cz));
          o.t[n].i0 = lindex(ax + cx, ay + cy, az + cz);
          o.t[n].i1 = lindex(ax + bx, ay + by, az + bz);
          o.t[n].i2 = lindex(bx + cx, by + cy, bz + cz);
          o.t[n].key = key;
          o.t[n].p = (float)(pa * pb * pc);
          ++n;
        }
      }
    }
    ++key;
  }
  return o;
}
constexpr Tab3 TAB3 = build3();

} // namespace

// One thread = one (n,r) row x 4 channels (float4). Loads 20 float4 (stride
// NC floats between l's), evaluates the fully-unrolled polynomial, writes 8
// float4. All table indices/prefactors fold to compile-time constants.
__global__ __launch_bounds__(256) void symm_kernel(const float* __restrict__ in,
                                                   float* __restrict__ out,
                                                   int nr_total) {
  int tid = blockIdx.x * blockDim.x + threadIdx.x;
  if (tid >= nr_total * 4) return;
  int c4 = tid & 3;           // which float4 of the 16 channels
  long nr = tid >> 2;         // which (n, r) row

  const float4* __restrict__ inp =
      reinterpret_cast<const float4*>(in) + nr * (NL * NC / 4) + c4;
  float4 a[NL];
#pragma unroll
  for (int l = 0; l < NL; ++l) a[l] = inp[l * (NC / 4)];

  float4 acc[NKOUT];
  acc[0] = a[0];  // b1
#pragma unroll
  for (int k = 1; k < NKOUT; ++k) acc[k] = make_float4(0.f, 0.f, 0.f, 0.f);

  // nu2: acc[1+key] += p * a[i]^2
#pragma unroll
  for (int t = 0; t < NT2; ++t) {
    const float4 v = a[TAB2.t[t].i];
    const float  p = TAB2.t[t].p;
    float4& d = acc[1 + TAB2.t[t].key];
    d.x = fmaf(p * v.x, v.x, d.x);
    d.y = fmaf(p * v.y, v.y, d.y);
    d.z = fmaf(p * v.z, v.z, d.z);
    d.w = fmaf(p * v.w, v.w, d.w);
  }

  // nu3: acc[1+K2+key] += p * a[i0]*a[i1]*a[i2]
#pragma unroll
  for (int t = 0; t < NT3; ++t) {
    const float4 u = a[TAB3.t[t].i0];
    const float4 v = a[TAB3.t[t].i1];
    const float4 w = a[TAB3.t[t].i2];
    const float  p = TAB3.t[t].p;
    float4& d = acc[1 + K2 + TAB3.t[t].key];
    d.x = fmaf(p * (u.x * v.x), w.x, d.x);
    d.y = fmaf(p * (u.y * v.y), w.y, d.y);
    d.z = fmaf(p * (u.z * v.z), w.z, d.z);
    d.w = fmaf(p * (u.w * v.w), w.w, d.w);
  }

  float4* __restrict__ op =
      reinterpret_cast<float4*>(out) + nr * (NKOUT * NC / 4) + c4;
#pragma unroll
  for (int k = 0; k < NKOUT; ++k) op[k * (NC / 4)] = acc[k];
}

extern "C" void kernel_launch(void* const* d_in, const int* in_sizes, int n_in,
                              void* d_out, int out_size, void* d_ws, size_t ws_size,
                              hipStream_t stream) {
  const float* in = (const float*)d_in[0];
  float* out = (float*)d_out;
  int nr_total = in_sizes[0] / (NL * NC);   // 4000 * 8 = 32000
  int total = nr_total * 4;                 // one thread per 4 channels
  int block = 256;
  int grid = (total + block - 1) / block;
  hipLaunchKernelGGL(symm_kernel, dim3(grid), dim3(block), 0, stream,
                     in, out, nr_total);
}

// Round 2
// 14.441 us; speedup vs baseline: 1.0633x; 1.0633x over previous
//
#include <hip/hip_runtime.h>

namespace {

constexpr int MAXL = 3;
constexpr int NL   = 20;   // len(L_LIST)
constexpr int NC   = 16;   // channels
constexpr int K2   = 3;
constexpr int K3   = 4;
constexpr int NKOUT = 1 + K2 + K3;  // 8 output "l" slots
constexpr int NT2  = 19;
constexpr int NT3  = 189;

constexpr int fact(int k) { return k <= 1 ? 1 : k * fact(k - 1); }

// Mirrors Python _l_list ordering: l ascending, lx descending, ly descending.
constexpr int lindex(int lx, int ly, int lz) {
  int idx = 0;
  for (int l = 0; l <= MAXL; ++l)
    for (int ax = l; ax >= 0; --ax)
      for (int ay = l - ax; ay >= 0; --ay) {
        int az = l - ax - ay;
        if (ax == lx && ay == ly && az == lz) return idx;
        ++idx;
      }
  return -1;
}

struct T2 { int i; int key; float p; };
struct Tab2 { T2 t[NT2]; };
constexpr Tab2 build2() {
  Tab2 o{}; int n = 0; int key = 0;
  for (int l = 1; l <= MAXL; ++l) {
    for (int ax = 0; ax <= l; ++ax)
      for (int ay = 0; ay <= l - ax; ++ay) {
        int az = l - ax - ay;
        int p = fact(l) / (fact(ax) * fact(ay) * fact(az));
        o.t[n].i = lindex(ax, ay, az);
        o.t[n].key = key;
        o.t[n].p = (float)p;
        ++n;
      }
    ++key;
  }
  return o;
}
constexpr Tab2 TAB2 = build2();

struct T3 { int i0, i1, i2, key; float p; };
struct Tab3 { T3 t[NT3]; };
constexpr Tab3 build3() {
  Tab3 o{}; int n = 0; int key = 0;
  for (int k12 = 1; k12 <= MAXL; ++k12)
  for (int k23 = 1; k23 <= MAXL; ++k23)
  for (int k13 = 1; k13 <= MAXL; ++k13) {
    if (k12 + k13 > MAXL || k12 + k23 > MAXL || k23 + k13 > MAXL) continue;
    for (int ax = 0; ax <= k12; ++ax)
    for (int ay = 0; ay <= k12 - ax; ++ay) {
      int az = k12 - ax - ay;
      int pa = fact(k12) / (fact(ax) * fact(ay) * fact(az));
      for (int bx = 0; bx <= k23; ++bx)
      for (int by = 0; by <= k23 - bx; ++by) {
        int bz = k23 - bx - by;
        int pb = fact(k23) / (fact(bx) * fact(by) * fact(bz));
        for (int cx = 0; cx <= k13; ++cx)
        for (int cy = 0; cy <= k13 - cx; ++cy) {
          int cz = k13 - cx - cy;
          int pc = fact(k13) / (fact(cx) * fact(cy) * fact(cz));
          o.t[n].i0 = lindex(ax + cx, ay + cy, az + cz);
          o.t[n].i1 = lindex(ax + bx, ay + by, az + bz);
          o.t[n].i2 = lindex(bx + cx, by + cy, bz + cz);
          o.t[n].key = key;
          o.t[n].p = (float)(pa * pb * pc);
          ++n;
        }
      }
    }
    ++key;
  }
  return o;
}
constexpr Tab3 TAB3 = build3();

} // namespace

// One thread = one (row, channel) scalar. 32000*16 = 512k threads = 8192
// waves = 8 waves/SIMD -> latency hiding. 16 consecutive lanes read 64 B
// contiguous per l (full coalescing). All table indices/prefactors fold to
// compile-time constants; ~610 VALU instrs/thread, hidden under the memory
// stream.
__global__ __launch_bounds__(256) void symm_kernel(const float* __restrict__ in,
                                                   float* __restrict__ out,
                                                   int rows) {
  int tid = blockIdx.x * blockDim.x + threadIdx.x;
  if (tid >= rows * NC) return;
  int c = tid & (NC - 1);
  long row = tid >> 4;

  const float* __restrict__ inp = in + row * (long)(NL * NC) + c;
  float a[NL];
#pragma unroll
  for (int l = 0; l < NL; ++l) a[l] = inp[l * NC];

  float acc[NKOUT];
  acc[0] = a[0];  // b1
#pragma unroll
  for (int k = 1; k < NKOUT; ++k) acc[k] = 0.f;

  // nu2: acc[1+key] += p * a[i]^2
#pragma unroll
  for (int t = 0; t < NT2; ++t) {
    const float v = a[TAB2.t[t].i];
    acc[1 + TAB2.t[t].key] = fmaf(TAB2.t[t].p * v, v, acc[1 + TAB2.t[t].key]);
  }

  // nu3: acc[1+K2+key] += p * a[i0]*a[i1]*a[i2]
#pragma unroll
  for (int t = 0; t < NT3; ++t) {
    const float u = a[TAB3.t[t].i0];
    const float v = a[TAB3.t[t].i1];
    const float w = a[TAB3.t[t].i2];
    acc[1 + K2 + TAB3.t[t].key] =
        fmaf(TAB3.t[t].p * (u * v), w, acc[1 + K2 + TAB3.t[t].key]);
  }

  float* __restrict__ op = out + row * (long)(NKOUT * NC) + c;
#pragma unroll
  for (int k = 0; k < NKOUT; ++k) op[k * NC] = acc[k];
}

extern "C" void kernel_launch(void* const* d_in, const int* in_sizes, int n_in,
                              void* d_out, int out_size, void* d_ws, size_t ws_size,
                              hipStream_t stream) {
  const float* in = (const float*)d_in[0];
  float* out = (float*)d_out;
  int rows = in_sizes[0] / (NL * NC);       // 4000 * 8 = 32000
  int total = rows * NC;                    // one thread per channel
  int block = 256;
  int grid = (total + block - 1) / block;
  hipLaunchKernelGGL(symm_kernel, dim3(grid), dim3(block), 0, stream,
                     in, out, rows);
}